// Round 8
// baseline (393.138 us; speedup 1.0000x reference)
//
#include <hip/hip_runtime.h>
#include <math.h>

#define N_NODES  50000
#define N_EDGES  800000
#define N_GRAPHS 5000
#define N_PAIRS  4096
#define F_IN     9
#define H        64
#define NCHUNK   49   // ceil(50000/1024)
#define WPAD     68   // transposed-weight row stride: 272B = 16B-aligned
#define FILL_PASS 8
#define FILL_RANGE 6250   // N_NODES / FILL_PASS

__device__ __forceinline__ float fast_tanh(float x) {
    float e = __expf(-2.0f * fabsf(x));
    float t = __fdividef(1.0f - e, 1.0f + e);
    return copysignf(t, x);
}

__device__ __forceinline__ float bf2f(unsigned short u) {
    union { unsigned int i; float f; } v; v.i = ((unsigned int)u) << 16; return v.f;
}
__device__ __forceinline__ unsigned short f2bf(float f) {
    union { float f; unsigned int i; } v; v.f = f;
    unsigned int u = v.i;
    return (unsigned short)((u + 0x7FFFu + ((u >> 16) & 1u)) >> 16);
}

// ---------------- degree + graph counts (merged) ----------------

__global__ void k_deg_cnt(const int* __restrict__ dst, const int* __restrict__ batch,
                          int* __restrict__ degi, float* __restrict__ cnt) {
    int i = blockIdx.x * blockDim.x + threadIdx.x;
    if (i < N_EDGES) atomicAdd(&degi[dst[i]], 1);
    if (i < N_NODES) atomicAdd(&cnt[batch[i]], 1.0f);
}

// ---------------- dis + chunk sums (merged) ----------------

__global__ void k_dis_chunksum(const int* __restrict__ degi, float* __restrict__ dis,
                               int* __restrict__ chunksum) {
    __shared__ int wsum[4];
    int t = threadIdx.x, lane = t & 63, wi = t >> 6;
    int base_i = blockIdx.x * 1024 + t * 4;
    int s = 0;
#pragma unroll
    for (int k = 0; k < 4; ++k) {
        int i = base_i + k;
        if (i < N_NODES) {
            int dg = degi[i];
            s += dg;
            dis[i] = rsqrtf((float)dg + 1.0f);
        }
    }
    for (int o = 32; o > 0; o >>= 1) s += __shfl_down(s, o, 64);
    if (lane == 0) wsum[wi] = s;
    __syncthreads();
    if (t == 0) chunksum[blockIdx.x] = wsum[0] + wsum[1] + wsum[2] + wsum[3];
}

__global__ void k_scanchunks(const int* __restrict__ chunksum, int* __restrict__ chunkbase,
                             int* __restrict__ off) {
    int lane = threadIdx.x;
    int v = (lane < NCHUNK) ? chunksum[lane] : 0;
    int inc = v;
    for (int o = 1; o < 64; o <<= 1) {
        int u = __shfl_up(inc, o, 64);
        if (lane >= o) inc += u;
    }
    if (lane < NCHUNK) chunkbase[lane] = inc - v;
    if (lane == 0) off[N_NODES] = N_EDGES;
}

__global__ void k_scan(const int* __restrict__ degi, const int* __restrict__ chunkbase,
                       int* __restrict__ off, int* __restrict__ cur) {
    __shared__ int wsum[4];
    int t = threadIdx.x, lane = t & 63, wi = t >> 6;
    int base_i = blockIdx.x * 1024 + t * 4;
    int v[4];
    int s = 0;
#pragma unroll
    for (int k = 0; k < 4; ++k) {
        int i = base_i + k;
        v[k] = (i < N_NODES) ? degi[i] : 0;
        s += v[k];
    }
    int inc = s;
    for (int o = 1; o < 64; o <<= 1) {
        int u = __shfl_up(inc, o, 64);
        if (lane >= o) inc += u;
    }
    if (lane == 63) wsum[wi] = inc;
    __syncthreads();
    int wbase = 0;
    for (int w = 0; w < 4; ++w) if (w < wi) wbase += wsum[w];
    int ex = chunkbase[blockIdx.x] + wbase + inc - s;
#pragma unroll
    for (int k = 0; k < 4; ++k) {
        int i = base_i + k;
        if (i < N_NODES) { off[i] = ex; cur[i] = ex; }
        ex += v[k];
    }
}

// packed CSR entry: low32 = src index, high32 = norm (f32 bits).
// 8 dst-range passes: writes into each ~0.8MB CSR window cluster in time so
// multiple 8B stores merge per cache line before writeback.
__global__ void k_fill(const int* __restrict__ src, const int* __restrict__ dst,
                       const float* __restrict__ dis, int* __restrict__ cur,
                       unsigned long long* __restrict__ csr_pack) {
    int tid = blockIdx.x * blockDim.x + threadIdx.x;
    if (tid >= N_EDGES) return;
    int d = dst[tid];
    for (int p = 0; p < FILL_PASS; ++p) {
        int lo = p * FILL_RANGE;
        if ((unsigned)(d - lo) < (unsigned)FILL_RANGE) {
            int s = src[tid];
            int pos = atomicAdd(&cur[d], 1);
            union { float f; unsigned int i; } nb;
            nb.f = dis[s] * dis[d];
            csr_pack[pos] = (unsigned long long)(unsigned int)s
                          | ((unsigned long long)nb.i << 32);
        }
    }
}

// ---------------- layer 1: aggregate x (9-wide), then fused mm+bias+tanh ----------------

__global__ void k_agg9(const float* __restrict__ x, const int* __restrict__ off,
                       const unsigned long long* __restrict__ csr_pack,
                       const float* __restrict__ dis, float* __restrict__ ax) {
    int g = threadIdx.x >> 4;
    int j = threadIdx.x & 15;
    int node = blockIdx.x * 16 + g;
    if (node >= N_NODES || j >= F_IN) return;
    int beg = off[node], end = off[node + 1];
    float d = dis[node];
    float acc = x[node * F_IN + j] * d * d;
    for (int e = beg; e < end; ++e) {
        unsigned long long p = csr_pack[e];
        int s = (int)(unsigned int)p;
        union { unsigned int i; float f; } nb; nb.i = (unsigned int)(p >> 32);
        acc += x[s * F_IN + j] * nb.f;
    }
    ax[node * F_IN + j] = acc;
}

__global__ void k_mm_in(const float* __restrict__ ax, const float* __restrict__ W,
                        const float* __restrict__ b, unsigned short* __restrict__ h) {
    __shared__ float sW[F_IN * H];
    __shared__ float sb[H];
    for (int t = threadIdx.x; t < F_IN * H; t += 256) sW[t] = W[t];
    if (threadIdx.x < H) sb[threadIdx.x] = b[threadIdx.x];
    __syncthreads();
    int wi = threadIdx.x >> 6, j = threadIdx.x & 63;
    for (int r = 0; r < 4; ++r) {
        int row = blockIdx.x * 16 + wi * 4 + r;
        if (row >= N_NODES) break;
        float acc = sb[j];
#pragma unroll
        for (int k = 0; k < F_IN; ++k) acc += ax[row * F_IN + k] * sW[k * H + j];
        h[row * H + j] = f2bf(fast_tanh(acc));
    }
}

// ---------------- fused layer: gather(h bf16) -> @W + b -> tanh -> bf16 ----------------
// 4 waves/block, 8 nodes/wave as TWO interleaved streams (A: it, B: it+4):
// lockstep main loop keeps 8 gather loads in flight per wave.

__global__ __launch_bounds__(256) void k_gmm(
        const unsigned short* __restrict__ hin, const int* __restrict__ off,
        const unsigned long long* __restrict__ csr_pack,
        const float* __restrict__ dis, const float* __restrict__ W,
        const float* __restrict__ b, unsigned short* __restrict__ hout) {
    __shared__ float sWt[H][WPAD];   // sWt[j][k] = W[k][j]
    __shared__ float sb[H];
    __shared__ float srow[8][H];     // [wave*2 + stream]
    for (int t = threadIdx.x; t < H * H; t += 256) {
        int k = t >> 6, jx = t & 63;
        sWt[jx][k] = W[t];
    }
    if (threadIdx.x < H) sb[threadIdx.x] = b[threadIdx.x];
    __syncthreads();
    int wi = threadIdx.x >> 6, j = threadIdx.x & 63;
    int base = blockIdx.x * 32 + wi * 8;

    for (int it = 0; it < 4; ++it) {
        int nA = base + it, nB = base + it + 4;
        bool okA = nA < N_NODES, okB = nB < N_NODES;
        int eA = 0, endA = 0, eB = 0, endB = 0;
        float accA = 0.f, accB = 0.f;
        if (okA) {
            eA = off[nA]; endA = off[nA + 1];
            float d = dis[nA];
            accA = bf2f(hin[nA * H + j]) * d * d;
        }
        if (okB) {
            eB = off[nB]; endB = off[nB + 1];
            float d = dis[nB];
            accB = bf2f(hin[nB * H + j]) * d * d;
        }
        // lockstep: 4+4 packs, then 4+4 gathers in flight
        while (eA + 3 < endA && eB + 3 < endB) {
            unsigned long long a0 = csr_pack[eA],     a1 = csr_pack[eA + 1];
            unsigned long long a2 = csr_pack[eA + 2], a3 = csr_pack[eA + 3];
            unsigned long long b0 = csr_pack[eB],     b1 = csr_pack[eB + 1];
            unsigned long long b2 = csr_pack[eB + 2], b3 = csr_pack[eB + 3];
            float vA0 = bf2f(hin[(unsigned int)a0 * H + j]);
            float vA1 = bf2f(hin[(unsigned int)a1 * H + j]);
            float vA2 = bf2f(hin[(unsigned int)a2 * H + j]);
            float vA3 = bf2f(hin[(unsigned int)a3 * H + j]);
            float vB0 = bf2f(hin[(unsigned int)b0 * H + j]);
            float vB1 = bf2f(hin[(unsigned int)b1 * H + j]);
            float vB2 = bf2f(hin[(unsigned int)b2 * H + j]);
            float vB3 = bf2f(hin[(unsigned int)b3 * H + j]);
            union { unsigned int i; float f; } nA0, nA1, nA2, nA3, nB0, nB1, nB2, nB3;
            nA0.i = (unsigned int)(a0 >> 32); nA1.i = (unsigned int)(a1 >> 32);
            nA2.i = (unsigned int)(a2 >> 32); nA3.i = (unsigned int)(a3 >> 32);
            nB0.i = (unsigned int)(b0 >> 32); nB1.i = (unsigned int)(b1 >> 32);
            nB2.i = (unsigned int)(b2 >> 32); nB3.i = (unsigned int)(b3 >> 32);
            accA += (vA0 * nA0.f + vA1 * nA1.f) + (vA2 * nA2.f + vA3 * nA3.f);
            accB += (vB0 * nB0.f + vB1 * nB1.f) + (vB2 * nB2.f + vB3 * nB3.f);
            eA += 4; eB += 4;
        }
        // drain stream A
        for (; eA + 3 < endA; eA += 4) {
            unsigned long long a0 = csr_pack[eA],     a1 = csr_pack[eA + 1];
            unsigned long long a2 = csr_pack[eA + 2], a3 = csr_pack[eA + 3];
            float v0 = bf2f(hin[(unsigned int)a0 * H + j]);
            float v1 = bf2f(hin[(unsigned int)a1 * H + j]);
            float v2 = bf2f(hin[(unsigned int)a2 * H + j]);
            float v3 = bf2f(hin[(unsigned int)a3 * H + j]);
            union { unsigned int i; float f; } n0, n1, n2, n3;
            n0.i = (unsigned int)(a0 >> 32); n1.i = (unsigned int)(a1 >> 32);
            n2.i = (unsigned int)(a2 >> 32); n3.i = (unsigned int)(a3 >> 32);
            accA += (v0 * n0.f + v1 * n1.f) + (v2 * n2.f + v3 * n3.f);
        }
        for (; eA < endA; ++eA) {
            unsigned long long p = csr_pack[eA];
            union { unsigned int i; float f; } nb; nb.i = (unsigned int)(p >> 32);
            accA += bf2f(hin[(unsigned int)p * H + j]) * nb.f;
        }
        // drain stream B
        for (; eB + 3 < endB; eB += 4) {
            unsigned long long b0 = csr_pack[eB],     b1 = csr_pack[eB + 1];
            unsigned long long b2 = csr_pack[eB + 2], b3 = csr_pack[eB + 3];
            float v0 = bf2f(hin[(unsigned int)b0 * H + j]);
            float v1 = bf2f(hin[(unsigned int)b1 * H + j]);
            float v2 = bf2f(hin[(unsigned int)b2 * H + j]);
            float v3 = bf2f(hin[(unsigned int)b3 * H + j]);
            union { unsigned int i; float f; } n0, n1, n2, n3;
            n0.i = (unsigned int)(b0 >> 32); n1.i = (unsigned int)(b1 >> 32);
            n2.i = (unsigned int)(b2 >> 32); n3.i = (unsigned int)(b3 >> 32);
            accB += (v0 * n0.f + v1 * n1.f) + (v2 * n2.f + v3 * n3.f);
        }
        for (; eB < endB; ++eB) {
            unsigned long long p = csr_pack[eB];
            union { unsigned int i; float f; } nb; nb.i = (unsigned int)(p >> 32);
            accB += bf2f(hin[(unsigned int)p * H + j]) * nb.f;
        }

        // epilogue: both streams share the per-lane weight reads
        srow[wi * 2][j]     = accA;   // wave-local: LDS ops in-order per wave
        srow[wi * 2 + 1][j] = accB;
        float aA = sb[j], aB = sb[j];
#pragma unroll
        for (int kb = 0; kb < H; kb += 4) {
            float4 w4 = *(const float4*)&sWt[j][kb];       // per-lane b128
            float4 gA = *(const float4*)&srow[wi * 2][kb]; // uniform broadcast
            float4 gB = *(const float4*)&srow[wi * 2 + 1][kb];
            aA += gA.x * w4.x + gA.y * w4.y + gA.z * w4.z + gA.w * w4.w;
            aB += gB.x * w4.x + gB.y * w4.y + gB.z * w4.z + gB.w * w4.w;
        }
        if (okA) hout[nA * H + j] = f2bf(fast_tanh(aA));
        if (okB) hout[nB * H + j] = f2bf(fast_tanh(aB));
    }
}

// ---------------- fused MLP + graph pool ----------------

__global__ __launch_bounds__(256) void k_mlp(
        const unsigned short* __restrict__ h, const int* __restrict__ batch,
        const float* __restrict__ fc1w, const float* __restrict__ fc1b,
        const float* __restrict__ fc2w, const float* __restrict__ fc2b,
        const float* __restrict__ fc3w, const float* __restrict__ fc3b,
        float* __restrict__ sums) {
    __shared__ float s1t[H][WPAD];    // s1t[j][k] = fc1w[k*H+j]
    __shared__ float s2t[32][WPAD];   // s2t[j][k] = fc2w[k*32+j]
    __shared__ float s3[32];
    __shared__ float sb1[H];
    __shared__ float sb2[32];
    __shared__ float srow[4][H];
    __shared__ float s1out[4][H];

    for (int t = threadIdx.x; t < H * H; t += 256) {
        int k = t >> 6, jx = t & 63;
        s1t[jx][k] = fc1w[t];
    }
    for (int t = threadIdx.x; t < H * 32; t += 256) {
        int k = t >> 5, jx = t & 31;
        s2t[jx][k] = fc2w[t];
    }
    if (threadIdx.x < 32) s3[threadIdx.x] = fc3w[threadIdx.x];
    if (threadIdx.x < H)  sb1[threadIdx.x] = fc1b[threadIdx.x];
    if (threadIdx.x < 32) sb2[threadIdx.x] = fc2b[threadIdx.x];
    __syncthreads();

    int wi = threadIdx.x >> 6, j = threadIdx.x & 63;
    int jj = j & 31, kb0 = (j >> 5) << 5;
    float b3 = fc3b[0];

    for (int it = 0; it < 8; ++it) {
        int node = blockIdx.x * 32 + wi * 8 + it;
        if (node >= N_NODES) break;

        srow[wi][j] = bf2f(h[node * H + j]);

        float a1 = sb1[j];
#pragma unroll
        for (int kb = 0; kb < H; kb += 4) {
            float4 g4 = *(const float4*)&srow[wi][kb];
            float4 w4 = *(const float4*)&s1t[j][kb];
            a1 += g4.x * w4.x + g4.y * w4.y + g4.z * w4.z + g4.w * w4.w;
        }
        a1 = fast_tanh(a1);
        s1out[wi][j] = a1;

        float a2 = 0.f;
#pragma unroll
        for (int kb = 0; kb < 32; kb += 4) {
            float4 g4 = *(const float4*)&s1out[wi][kb0 + kb];
            float4 w4 = *(const float4*)&s2t[jj][kb0 + kb];
            a2 += g4.x * w4.x + g4.y * w4.y + g4.z * w4.z + g4.w * w4.w;
        }
        a2 += __shfl_xor(a2, 32);             // combine k-halves
        float val = fast_tanh(a2 + sb2[jj]) * s3[jj];
        for (int o = 16; o > 0; o >>= 1) val += __shfl_xor(val, o);
        if (j == 0) atomicAdd(&sums[batch[node]], val + b3);
    }
}

// ---------------- readout ----------------

__global__ void k_finish(const float* __restrict__ sums, const float* __restrict__ cnt,
                         const int* __restrict__ ia, const int* __restrict__ ib,
                         float* __restrict__ out_pairs, float* __restrict__ out_util) {
    int i = blockIdx.x * blockDim.x + threadIdx.x;
    if (i < N_GRAPHS) out_util[i] = sums[i] / fmaxf(cnt[i], 1.0f);
    if (i < N_PAIRS) {
        int a = ia[i], b = ib[i];
        float ua = sums[a] / fmaxf(cnt[a], 1.0f);
        float ub = sums[b] / fmaxf(cnt[b], 1.0f);
        out_pairs[i] = 1.0f / (1.0f + __expf(-(ub - ua)));
    }
}

// ---------------- launch ----------------

extern "C" void kernel_launch(void* const* d_in, const int* in_sizes, int n_in,
                              void* d_out, int out_size, void* d_ws, size_t ws_size,
                              hipStream_t stream) {
    const float* x     = (const float*)d_in[0];
    const int*   ei    = (const int*)d_in[1];
    const int*   batch = (const int*)d_in[2];
    const int*   idx_a = (const int*)d_in[3];
    const int*   idx_b = (const int*)d_in[4];
    const float* W_in  = (const float*)d_in[5];
    const float* b_in  = (const float*)d_in[6];
    const float* W_h   = (const float*)d_in[7];
    const float* b_h   = (const float*)d_in[8];
    const float* W_out = (const float*)d_in[9];
    const float* b_out = (const float*)d_in[10];
    const float* fc1_w = (const float*)d_in[11];
    const float* fc1_b = (const float*)d_in[12];
    const float* fc2_w = (const float*)d_in[13];
    const float* fc2_b = (const float*)d_in[14];
    const float* fc3_w = (const float*)d_in[15];
    const float* fc3_b = (const float*)d_in[16];

    const int* src = ei;
    const int* dst = ei + N_EDGES;

    char* wsb = (char*)d_ws;
    // zero-region (one memset): degi, cnt, sums
    int*   degi     = (int*)wsb;    wsb += N_NODES * 4;
    float* cnt      = (float*)wsb;  wsb += N_GRAPHS * 4;
    float* sums     = (float*)wsb;  wsb += N_GRAPHS * 4;
    float* dis      = (float*)wsb;  wsb += N_NODES * 4;
    float* ax       = (float*)wsb;  wsb += (size_t)N_NODES * F_IN * 4;
    unsigned short* h0 = (unsigned short*)wsb;  wsb += (size_t)N_NODES * H * 2;
    unsigned short* h1 = (unsigned short*)wsb;  wsb += (size_t)N_NODES * H * 2;
    int*   offs     = (int*)wsb;    wsb += (N_NODES + 1) * 4;
    int*   cur      = (int*)wsb;    wsb += N_NODES * 4;
    int*   chunksum = (int*)wsb;    wsb += NCHUNK * 4;
    int*   chunkbase= (int*)wsb;    wsb += NCHUNK * 4;
    wsb = (char*)(((size_t)wsb + 7) & ~(size_t)7);
    unsigned long long* csr_pack = (unsigned long long*)wsb; wsb += (size_t)N_EDGES * 8;

    float* out_pairs = (float*)d_out;
    float* out_util  = out_pairs + N_PAIRS;

    hipMemsetAsync(degi, 0, (N_NODES + 2 * N_GRAPHS) * sizeof(int), stream);

    dim3 blk(256);
    k_deg_cnt<<<(N_EDGES + 255) / 256, blk, 0, stream>>>(dst, batch, degi, cnt);
    k_dis_chunksum<<<NCHUNK, blk, 0, stream>>>(degi, dis, chunksum);
    k_scanchunks<<<1, 64, 0, stream>>>(chunksum, chunkbase, offs);
    k_scan<<<NCHUNK, blk, 0, stream>>>(degi, chunkbase, offs, cur);
    k_fill<<<(N_EDGES + 255) / 256, blk, 0, stream>>>(src, dst, dis, cur, csr_pack);

    // layer 1: aggregate x (9-wide) then fused mm+bias+tanh
    k_agg9<<<(N_NODES + 15) / 16, blk, 0, stream>>>(x, offs, csr_pack, dis, ax);
    k_mm_in<<<(N_NODES + 15) / 16, blk, 0, stream>>>(ax, W_in, b_in, h0);

    const int gmm_blocks = (N_NODES + 31) / 32;
    // layers 2..4: fused gather+matmul+bias+tanh
    k_gmm<<<gmm_blocks, blk, 0, stream>>>(h0, offs, csr_pack, dis, W_h, b_h, h1);
    k_gmm<<<gmm_blocks, blk, 0, stream>>>(h1, offs, csr_pack, dis, W_h, b_h, h0);
    k_gmm<<<gmm_blocks, blk, 0, stream>>>(h0, offs, csr_pack, dis, W_out, b_out, h1);

    // MLP + pool
    k_mlp<<<(N_NODES + 31) / 32, blk, 0, stream>>>(h1, batch, fc1_w, fc1_b, fc2_w, fc2_b,
                                                   fc3_w, fc3_b, sums);
    k_finish<<<(N_GRAPHS + 255) / 256, blk, 0, stream>>>(sums, cnt, idx_a, idx_b,
                                                         out_pairs, out_util);
}

// Round 9
// 285.137 us; speedup vs baseline: 1.3788x; 1.3788x over previous
//
#include <hip/hip_runtime.h>
#include <math.h>

#define N_NODES  50000
#define N_EDGES  800000
#define N_GRAPHS 5000
#define N_PAIRS  4096
#define F_IN     9
#define H        64
#define NCHUNK   49   // ceil(50000/1024)
#define WPAD     68   // transposed-weight row stride: 272B = 16B-aligned

__device__ __forceinline__ float fast_tanh(float x) {
    float e = __expf(-2.0f * fabsf(x));
    float t = __fdividef(1.0f - e, 1.0f + e);
    return copysignf(t, x);
}

__device__ __forceinline__ float bf2f(unsigned short u) {
    union { unsigned int i; float f; } v; v.i = ((unsigned int)u) << 16; return v.f;
}
__device__ __forceinline__ unsigned short f2bf(float f) {
    union { float f; unsigned int i; } v; v.f = f;
    unsigned int u = v.i;
    return (unsigned short)((u + 0x7FFFu + ((u >> 16) & 1u)) >> 16);
}

__device__ __forceinline__ int lbound(const int* __restrict__ a, int n, int v) {
    int lo = 0, hi = n;
    while (lo < hi) { int m = (lo + hi) >> 1; if (a[m] < v) lo = m + 1; else hi = m; }
    return lo;
}

// ---------------- degree + per-edge rank (atomic return value IS the rank) --------

__global__ void k_deg_rank(const int* __restrict__ dst, int* __restrict__ degi,
                           unsigned char* __restrict__ rank) {
    int i = blockIdx.x * blockDim.x + threadIdx.x;
    if (i < N_EDGES) rank[i] = (unsigned char)atomicAdd(&degi[dst[i]], 1);
}

// ---------------- dis + chunk sums (merged) ----------------

__global__ void k_dis_chunksum(const int* __restrict__ degi, float* __restrict__ dis,
                               int* __restrict__ chunksum) {
    __shared__ int wsum[4];
    int t = threadIdx.x, lane = t & 63, wi = t >> 6;
    int base_i = blockIdx.x * 1024 + t * 4;
    int s = 0;
#pragma unroll
    for (int k = 0; k < 4; ++k) {
        int i = base_i + k;
        if (i < N_NODES) {
            int dg = degi[i];
            s += dg;
            dis[i] = rsqrtf((float)dg + 1.0f);
        }
    }
    for (int o = 32; o > 0; o >>= 1) s += __shfl_down(s, o, 64);
    if (lane == 0) wsum[wi] = s;
    __syncthreads();
    if (t == 0) chunksum[blockIdx.x] = wsum[0] + wsum[1] + wsum[2] + wsum[3];
}

__global__ void k_scanchunks(const int* __restrict__ chunksum, int* __restrict__ chunkbase,
                             int* __restrict__ off) {
    int lane = threadIdx.x;
    int v = (lane < NCHUNK) ? chunksum[lane] : 0;
    int inc = v;
    for (int o = 1; o < 64; o <<= 1) {
        int u = __shfl_up(inc, o, 64);
        if (lane >= o) inc += u;
    }
    if (lane < NCHUNK) chunkbase[lane] = inc - v;
    if (lane == 0) off[N_NODES] = N_EDGES;
}

__global__ void k_scan(const int* __restrict__ degi, const int* __restrict__ chunkbase,
                       int* __restrict__ off) {
    __shared__ int wsum[4];
    int t = threadIdx.x, lane = t & 63, wi = t >> 6;
    int base_i = blockIdx.x * 1024 + t * 4;
    int v[4];
    int s = 0;
#pragma unroll
    for (int k = 0; k < 4; ++k) {
        int i = base_i + k;
        v[k] = (i < N_NODES) ? degi[i] : 0;
        s += v[k];
    }
    int inc = s;
    for (int o = 1; o < 64; o <<= 1) {
        int u = __shfl_up(inc, o, 64);
        if (lane >= o) inc += u;
    }
    if (lane == 63) wsum[wi] = inc;
    __syncthreads();
    int wbase = 0;
    for (int w = 0; w < 4; ++w) if (w < wi) wbase += wsum[w];
    int ex = chunkbase[blockIdx.x] + wbase + inc - s;
#pragma unroll
    for (int k = 0; k < 4; ++k) {
        int i = base_i + k;
        if (i < N_NODES) off[i] = ex;
        ex += v[k];
    }
}

// packed CSR entry: low32 = src index, high32 = norm (f32 bits).
// pos = off[dst] + rank  -> NO atomic in this kernel.
__global__ void k_fill(const int* __restrict__ src, const int* __restrict__ dst,
                       const unsigned char* __restrict__ rank,
                       const float* __restrict__ dis, const int* __restrict__ off,
                       unsigned long long* __restrict__ csr_pack) {
    int e = blockIdx.x * blockDim.x + threadIdx.x;
    if (e < N_EDGES) {
        int s = src[e], d = dst[e];
        int pos = off[d] + (int)rank[e];
        union { float f; unsigned int i; } nb;
        nb.f = dis[s] * dis[d];
        csr_pack[pos] = (unsigned long long)(unsigned int)s
                      | ((unsigned long long)nb.i << 32);
    }
}

// ---------------- layer 1: aggregate x (9-wide), then fused mm+bias+tanh ----------------

__global__ void k_agg9(const float* __restrict__ x, const int* __restrict__ off,
                       const unsigned long long* __restrict__ csr_pack,
                       const float* __restrict__ dis, float* __restrict__ ax) {
    int g = threadIdx.x >> 4;
    int j = threadIdx.x & 15;
    int node = blockIdx.x * 16 + g;
    if (node >= N_NODES || j >= F_IN) return;
    int beg = off[node], end = off[node + 1];
    float d = dis[node];
    float acc = x[node * F_IN + j] * d * d;
    for (int e = beg; e < end; ++e) {
        unsigned long long p = csr_pack[e];
        int s = (int)(unsigned int)p;
        union { unsigned int i; float f; } nb; nb.i = (unsigned int)(p >> 32);
        acc += x[s * F_IN + j] * nb.f;
    }
    ax[node * F_IN + j] = acc;
}

__global__ void k_mm_in(const float* __restrict__ ax, const float* __restrict__ W,
                        const float* __restrict__ b, unsigned short* __restrict__ h) {
    __shared__ float sW[F_IN * H];
    __shared__ float sb[H];
    for (int t = threadIdx.x; t < F_IN * H; t += 256) sW[t] = W[t];
    if (threadIdx.x < H) sb[threadIdx.x] = b[threadIdx.x];
    __syncthreads();
    int wi = threadIdx.x >> 6, j = threadIdx.x & 63;
    for (int r = 0; r < 4; ++r) {
        int row = blockIdx.x * 16 + wi * 4 + r;
        if (row >= N_NODES) break;
        float acc = sb[j];
#pragma unroll
        for (int k = 0; k < F_IN; ++k) acc += ax[row * F_IN + k] * sW[k * H + j];
        h[row * H + j] = f2bf(fast_tanh(acc));
    }
}

// ---------------- fused layer: gather(h bf16) -> @W + b -> tanh -> bf16 ----------------
// 4 waves/block, 8 nodes/wave (R5 config: best measured).

__global__ __launch_bounds__(256) void k_gmm(
        const unsigned short* __restrict__ hin, const int* __restrict__ off,
        const unsigned long long* __restrict__ csr_pack,
        const float* __restrict__ dis, const float* __restrict__ W,
        const float* __restrict__ b, unsigned short* __restrict__ hout) {
    __shared__ float sWt[H][WPAD];   // sWt[j][k] = W[k][j]
    __shared__ float sb[H];
    __shared__ float srow[4][H];
    for (int t = threadIdx.x; t < H * H; t += 256) {
        int k = t >> 6, jx = t & 63;
        sWt[jx][k] = W[t];
    }
    if (threadIdx.x < H) sb[threadIdx.x] = b[threadIdx.x];
    __syncthreads();
    int wi = threadIdx.x >> 6, j = threadIdx.x & 63;
    for (int it = 0; it < 8; ++it) {
        int node = blockIdx.x * 32 + wi * 8 + it;
        if (node >= N_NODES) break;
        int beg = off[node], end = off[node + 1];
        float d = dis[node];
        float acc = bf2f(hin[node * H + j]) * d * d;
        int e = beg;
        for (; e + 3 < end; e += 4) {
            unsigned long long p0 = csr_pack[e],     p1 = csr_pack[e + 1];
            unsigned long long p2 = csr_pack[e + 2], p3 = csr_pack[e + 3];
            union { unsigned int i; float f; } n0, n1, n2, n3;
            n0.i = (unsigned int)(p0 >> 32); n1.i = (unsigned int)(p1 >> 32);
            n2.i = (unsigned int)(p2 >> 32); n3.i = (unsigned int)(p3 >> 32);
            float v0 = bf2f(hin[(unsigned int)p0 * H + j]);
            float v1 = bf2f(hin[(unsigned int)p1 * H + j]);
            float v2 = bf2f(hin[(unsigned int)p2 * H + j]);
            float v3 = bf2f(hin[(unsigned int)p3 * H + j]);
            acc += v0 * n0.f + v1 * n1.f + v2 * n2.f + v3 * n3.f;
        }
        for (; e < end; ++e) {
            unsigned long long p = csr_pack[e];
            union { unsigned int i; float f; } nb; nb.i = (unsigned int)(p >> 32);
            acc += bf2f(hin[(unsigned int)p * H + j]) * nb.f;
        }

        srow[wi][j] = acc;          // wave-local write then read: in-order per wave
        float a = sb[j];
#pragma unroll
        for (int kb = 0; kb < H; kb += 4) {
            float4 g4 = *(const float4*)&srow[wi][kb];   // uniform-addr broadcast
            float4 w4 = *(const float4*)&sWt[j][kb];     // per-lane b128
            a += g4.x * w4.x + g4.y * w4.y + g4.z * w4.z + g4.w * w4.w;
        }
        hout[node * H + j] = f2bf(fast_tanh(a));
    }
}

// ---------------- fused MLP + graph pool ----------------

__global__ __launch_bounds__(256) void k_mlp(
        const unsigned short* __restrict__ h, const int* __restrict__ batch,
        const float* __restrict__ fc1w, const float* __restrict__ fc1b,
        const float* __restrict__ fc2w, const float* __restrict__ fc2b,
        const float* __restrict__ fc3w, const float* __restrict__ fc3b,
        float* __restrict__ sums) {
    __shared__ float s1t[H][WPAD];    // s1t[j][k] = fc1w[k*H+j]
    __shared__ float s2t[32][WPAD];   // s2t[j][k] = fc2w[k*32+j]
    __shared__ float s3[32];
    __shared__ float sb1[H];
    __shared__ float sb2[32];
    __shared__ float srow[4][H];
    __shared__ float s1out[4][H];

    for (int t = threadIdx.x; t < H * H; t += 256) {
        int k = t >> 6, jx = t & 63;
        s1t[jx][k] = fc1w[t];
    }
    for (int t = threadIdx.x; t < H * 32; t += 256) {
        int k = t >> 5, jx = t & 31;
        s2t[jx][k] = fc2w[t];
    }
    if (threadIdx.x < 32) s3[threadIdx.x] = fc3w[threadIdx.x];
    if (threadIdx.x < H)  sb1[threadIdx.x] = fc1b[threadIdx.x];
    if (threadIdx.x < 32) sb2[threadIdx.x] = fc2b[threadIdx.x];
    __syncthreads();

    int wi = threadIdx.x >> 6, j = threadIdx.x & 63;
    int jj = j & 31, kb0 = (j >> 5) << 5;
    float b3 = fc3b[0];

    for (int it = 0; it < 8; ++it) {
        int node = blockIdx.x * 32 + wi * 8 + it;
        if (node >= N_NODES) break;

        srow[wi][j] = bf2f(h[node * H + j]);

        float a1 = sb1[j];
#pragma unroll
        for (int kb = 0; kb < H; kb += 4) {
            float4 g4 = *(const float4*)&srow[wi][kb];
            float4 w4 = *(const float4*)&s1t[j][kb];
            a1 += g4.x * w4.x + g4.y * w4.y + g4.z * w4.z + g4.w * w4.w;
        }
        a1 = fast_tanh(a1);
        s1out[wi][j] = a1;

        float a2 = 0.f;
#pragma unroll
        for (int kb = 0; kb < 32; kb += 4) {
            float4 g4 = *(const float4*)&s1out[wi][kb0 + kb];
            float4 w4 = *(const float4*)&s2t[jj][kb0 + kb];
            a2 += g4.x * w4.x + g4.y * w4.y + g4.z * w4.z + g4.w * w4.w;
        }
        a2 += __shfl_xor(a2, 32);             // combine k-halves
        float val = fast_tanh(a2 + sb2[jj]) * s3[jj];
        for (int o = 16; o > 0; o >>= 1) val += __shfl_xor(val, o);
        if (j == 0) atomicAdd(&sums[batch[node]], val + b3);
    }
}

// ---------------- readout: cnt via binary search on sorted batch ----------------

__global__ void k_util(const float* __restrict__ sums, const int* __restrict__ batch,
                       float* __restrict__ out_util) {
    int g = blockIdx.x * blockDim.x + threadIdx.x;
    if (g < N_GRAPHS) {
        int c = lbound(batch, N_NODES, g + 1) - lbound(batch, N_NODES, g);
        out_util[g] = sums[g] / fmaxf((float)c, 1.0f);
    }
}

__global__ void k_pairs(const float* __restrict__ u, const int* __restrict__ ia,
                        const int* __restrict__ ib, float* __restrict__ out) {
    int p = blockIdx.x * blockDim.x + threadIdx.x;
    if (p < N_PAIRS) {
        float d = u[ib[p]] - u[ia[p]];
        out[p] = 1.0f / (1.0f + __expf(-d));
    }
}

// ---------------- launch ----------------

extern "C" void kernel_launch(void* const* d_in, const int* in_sizes, int n_in,
                              void* d_out, int out_size, void* d_ws, size_t ws_size,
                              hipStream_t stream) {
    const float* x     = (const float*)d_in[0];
    const int*   ei    = (const int*)d_in[1];
    const int*   batch = (const int*)d_in[2];
    const int*   idx_a = (const int*)d_in[3];
    const int*   idx_b = (const int*)d_in[4];
    const float* W_in  = (const float*)d_in[5];
    const float* b_in  = (const float*)d_in[6];
    const float* W_h   = (const float*)d_in[7];
    const float* b_h   = (const float*)d_in[8];
    const float* W_out = (const float*)d_in[9];
    const float* b_out = (const float*)d_in[10];
    const float* fc1_w = (const float*)d_in[11];
    const float* fc1_b = (const float*)d_in[12];
    const float* fc2_w = (const float*)d_in[13];
    const float* fc2_b = (const float*)d_in[14];
    const float* fc3_w = (const float*)d_in[15];
    const float* fc3_b = (const float*)d_in[16];

    const int* src = ei;
    const int* dst = ei + N_EDGES;

    char* wsb = (char*)d_ws;
    // zero-region (one memset): degi, sums
    int*   degi     = (int*)wsb;    wsb += N_NODES * 4;
    float* sums     = (float*)wsb;  wsb += N_GRAPHS * 4;
    float* dis      = (float*)wsb;  wsb += N_NODES * 4;
    float* ax       = (float*)wsb;  wsb += (size_t)N_NODES * F_IN * 4;
    unsigned short* h0 = (unsigned short*)wsb;  wsb += (size_t)N_NODES * H * 2;
    unsigned short* h1 = (unsigned short*)wsb;  wsb += (size_t)N_NODES * H * 2;
    int*   offs     = (int*)wsb;    wsb += (N_NODES + 1) * 4;
    int*   chunksum = (int*)wsb;    wsb += NCHUNK * 4;
    int*   chunkbase= (int*)wsb;    wsb += NCHUNK * 4;
    unsigned char* rank = (unsigned char*)wsb;  wsb += N_EDGES;
    wsb = (char*)(((size_t)wsb + 7) & ~(size_t)7);
    unsigned long long* csr_pack = (unsigned long long*)wsb; wsb += (size_t)N_EDGES * 8;

    float* out_pairs = (float*)d_out;
    float* out_util  = out_pairs + N_PAIRS;

    hipMemsetAsync(degi, 0, (N_NODES + N_GRAPHS) * sizeof(int), stream);

    dim3 blk(256);
    k_deg_rank<<<(N_EDGES + 255) / 256, blk, 0, stream>>>(dst, degi, rank);
    k_dis_chunksum<<<NCHUNK, blk, 0, stream>>>(degi, dis, chunksum);
    k_scanchunks<<<1, 64, 0, stream>>>(chunksum, chunkbase, offs);
    k_scan<<<NCHUNK, blk, 0, stream>>>(degi, chunkbase, offs);
    k_fill<<<(N_EDGES + 255) / 256, blk, 0, stream>>>(src, dst, rank, dis, offs, csr_pack);

    // layer 1: aggregate x (9-wide) then fused mm+bias+tanh
    k_agg9<<<(N_NODES + 15) / 16, blk, 0, stream>>>(x, offs, csr_pack, dis, ax);
    k_mm_in<<<(N_NODES + 15) / 16, blk, 0, stream>>>(ax, W_in, b_in, h0);

    const int gmm_blocks = (N_NODES + 31) / 32;
    // layers 2..4: fused gather+matmul+bias+tanh
    k_gmm<<<gmm_blocks, blk, 0, stream>>>(h0, offs, csr_pack, dis, W_h, b_h, h1);
    k_gmm<<<gmm_blocks, blk, 0, stream>>>(h1, offs, csr_pack, dis, W_h, b_h, h0);
    k_gmm<<<gmm_blocks, blk, 0, stream>>>(h0, offs, csr_pack, dis, W_out, b_out, h1);

    // MLP + pool
    k_mlp<<<gmm_blocks, blk, 0, stream>>>(h1, batch, fc1_w, fc1_b, fc2_w, fc2_b,
                                          fc3_w, fc3_b, sums);
    k_util<<<(N_GRAPHS + 255) / 256, blk, 0, stream>>>(sums, batch, out_util);
    k_pairs<<<(N_PAIRS + 255) / 256, blk, 0, stream>>>(out_util, idx_a, idx_b, out_pairs);
}